// Round 5
// baseline (346.314 us; speedup 1.0000x reference)
//
#include <hip/hip_runtime.h>
#include <math.h>

// Problem constants (B=8, C=512, H=W=64)
constexpr int CB = 8;
constexpr int CC = 512;
constexpr int CN = 4096;   // H*W
constexpr int CM = 1024;   // pooled positions
constexpr int C8 = 64;     // C/8
constexpr int C2 = 256;    // C/2

typedef __attribute__((ext_vector_type(8))) short short8;
typedef __attribute__((ext_vector_type(8))) _Float16 half8;
typedef __attribute__((ext_vector_type(4))) float f32x4;

__device__ inline unsigned short f2bf(float f) {
  unsigned int u = __float_as_uint(f);
  return (unsigned short)((u + 0x7FFFu + ((u >> 16) & 1u)) >> 16);
}
__device__ inline unsigned short f16bits(float f) {
  union { _Float16 h; unsigned short u; } c;
  c.h = (_Float16)f;
  return c.u;
}

// Relaxed workgroup barrier: drains LDS ops only (lgkmcnt), NOT the vmcnt
// queue — prefetched global loads stay in flight across it. The "memory"
// clobbers pin LDS writes before / LDS reads after the s_barrier.
__device__ inline void barrier_lds_only() {
  asm volatile("s_waitcnt lgkmcnt(0)" ::: "memory");
  __builtin_amdgcn_s_barrier();
  asm volatile("" ::: "memory");
}

// ---------------------------------------------------------------------------
// Weight conversion: theta/phi -> f16 hi/lo (2-term), g -> f16, o -> bf16.
// ---------------------------------------------------------------------------
__global__ __launch_bounds__(256)
void conv_w(const float* __restrict__ wt, const float* __restrict__ wp,
            const float* __restrict__ wg, const float* __restrict__ wo,
            _Float16* __restrict__ wth, _Float16* __restrict__ wtl,
            _Float16* __restrict__ wph, _Float16* __restrict__ wpl,
            _Float16* __restrict__ wgf, unsigned short* __restrict__ woh) {
  const int i = blockIdx.x * 256 + threadIdx.x;
  if (i < 32768) {
    float a = wt[i];
    _Float16 h = (_Float16)a;
    wth[i] = h; wtl[i] = (_Float16)(a - (float)h);
    a = wp[i];
    h = (_Float16)a;
    wph[i] = h; wpl[i] = (_Float16)(a - (float)h);
  }
  wgf[i] = (_Float16)wg[i];
  woh[i] = f2bf(wo[i]);
}

// ---------------------------------------------------------------------------
// Transpose+convert: x fp32 [b][c][n] -> xT f16 [b][n][c].
// grid (64 n-tiles, 8 c-tiles, 8 b), 64x64 tiles.
// ---------------------------------------------------------------------------
__global__ __launch_bounds__(256)
void xpose(const float* __restrict__ X, _Float16* __restrict__ xT) {
  __shared__ __align__(16) float raw[64][68];
  const int b = blockIdx.z, c0 = blockIdx.y * 64, n0 = blockIdx.x * 64;
  const float* Xb = X + ((size_t)b * CC + c0) * CN + n0;
  const int tid = threadIdx.x;
#pragma unroll
  for (int it = 0; it < 4; ++it) {
    const int idx = it * 256 + tid;
    const int row = idx >> 4, col4 = (idx & 15) * 4;
    *(float4*)&raw[row][col4] = *(const float4*)&Xb[(size_t)row * CN + col4];
  }
  __syncthreads();
  unsigned short* Yb = (unsigned short*)(xT + ((size_t)b * CN + n0) * CC + c0);
#pragma unroll
  for (int it = 0; it < 4; ++it) {
    const int idx = it * 256 + tid;
    const int n = idx >> 4, c4 = (idx & 15) * 4;
    ushort4 o;
    o.x = f16bits(raw[c4 + 0][n]);
    o.y = f16bits(raw[c4 + 1][n]);
    o.z = f16bits(raw[c4 + 2][n]);
    o.w = f16bits(raw[c4 + 3][n]);
    *(ushort4*)&Yb[(size_t)n * CC + c4] = o;
  }
}

// ---------------------------------------------------------------------------
// theta projection v2: all 16 B-fragments up-front, weights streamed (L2-hot
// across 1024 blocks). Output thT[b][pos][64] f16 via LDS transpose.
// grid (128, 8).
// ---------------------------------------------------------------------------
__global__ __launch_bounds__(256, 2)
void proj_th2(const _Float16* __restrict__ Wh, const _Float16* __restrict__ Wl,
              const _Float16* __restrict__ xT, _Float16* __restrict__ thT) {
  __shared__ __align__(16) unsigned short LT[32][68];
  const int b = blockIdx.y, n0 = blockIdx.x * 32;
  const int tid = threadIdx.x;
  const int w = tid >> 6, l = tid & 63;
  const int l15 = l & 15, quad = l >> 4;
  const int wn = w & 1, wo = w >> 1;   // wave -> (n-half, oc-half)
  const _Float16* Brow = xT + (size_t)(b * CN + n0 + wn * 16 + l15) * CC;
  half8 bfr[16];
#pragma unroll
  for (int kk = 0; kk < 16; ++kk)
    bfr[kk] = *(const half8*)&Brow[kk * 32 + quad * 8];
  __builtin_amdgcn_sched_barrier(0);   // pin: all B loads issued before MFMAs
  f32x4 acc[2] = {};
#pragma unroll
  for (int kk = 0; kk < 16; ++kk) {
    const int k0 = kk * 32;
#pragma unroll
    for (int i = 0; i < 2; ++i) {
      const half8 ah = *(const half8*)&Wh[(size_t)(wo * 32 + i * 16 + l15) * CC +
                                          k0 + quad * 8];
      const half8 al = *(const half8*)&Wl[(size_t)(wo * 32 + i * 16 + l15) * CC +
                                          k0 + quad * 8];
      acc[i] = __builtin_amdgcn_mfma_f32_16x16x32_f16(ah, bfr[kk], acc[i], 0, 0, 0);
      acc[i] = __builtin_amdgcn_mfma_f32_16x16x32_f16(al, bfr[kk], acc[i], 0, 0, 0);
    }
  }
  // epilogue: LT[n][oc], n = col = l15, oc = A-row
#pragma unroll
  for (int i = 0; i < 2; ++i)
#pragma unroll
    for (int r = 0; r < 4; ++r)
      LT[wn * 16 + l15][wo * 32 + i * 16 + quad * 4 + r] = f16bits(acc[i][r]);
  __syncthreads();
  unsigned short* Yb = (unsigned short*)(thT + (size_t)(b * CN + n0) * C8);
#pragma unroll
  for (int it = 0; it < 2; ++it) {
    const int idx = it * 256 + tid;
    const int pos = idx >> 4, c4 = (idx & 15) * 4;
    ushort4 v = *(const ushort4*)&LT[pos][c4];
    *(ushort4*)&Yb[(size_t)pos * C8 + c4] = v;
  }
}

// ---------------------------------------------------------------------------
// phi + g projections with FUSED 2x2 maxpool epilogue.
// Depth-1 pipeline on B (xT) fragments. No barriers in the K loop, so the
// prefetch survives (compiler inserts counted vmcnt at first use).
// mt=0: phi (2-term) -> phT[b][m][64] f16; mt=1..4: g -> gbf[b][c2][m] bf16.
// grid (16, 5, 8).
// ---------------------------------------------------------------------------
__global__ __launch_bounds__(256)
void proj_pg(const _Float16* __restrict__ Wph, const _Float16* __restrict__ Wpl,
             const _Float16* __restrict__ Wg, const _Float16* __restrict__ xT,
             _Float16* __restrict__ phT, unsigned short* __restrict__ gbf) {
  __shared__ float Pbuf[2][64][33];
  const int b = blockIdx.z, mt = blockIdx.y, tile = blockIdx.x;
  const int n0 = tile * 256;
  const int tid = threadIdx.x;
  const int w = tid >> 6, l = tid & 63;
  const int l15 = l & 15, quad = l >> 4;
  const bool isphi = (mt == 0);
  const _Float16* Ah = isphi ? Wph : (Wg + (size_t)(mt - 1) * 64 * CC);
  f32x4 acc[4][4] = {};
  const _Float16* Bbase = xT + (size_t)(b * CN + n0 + w * 64) * CC;

  auto loadB = [&](half8 (&bf)[4], int k0) {
#pragma unroll
    for (int j = 0; j < 4; ++j)
      bf[j] = *(const half8*)&Bbase[(size_t)(j * 16 + l15) * CC + k0 + quad * 8];
  };
  auto doK = [&](half8 (&bf)[4], int k0) {
    half8 ah[4];
#pragma unroll
    for (int i = 0; i < 4; ++i)
      ah[i] = *(const half8*)&Ah[(size_t)(i * 16 + l15) * CC + k0 + quad * 8];
#pragma unroll
    for (int i = 0; i < 4; ++i)
#pragma unroll
      for (int j = 0; j < 4; ++j)
        acc[i][j] = __builtin_amdgcn_mfma_f32_16x16x32_f16(ah[i], bf[j], acc[i][j], 0, 0, 0);
    if (isphi) {
      half8 al[4];
#pragma unroll
      for (int i = 0; i < 4; ++i)
        al[i] = *(const half8*)&Wpl[(size_t)(i * 16 + l15) * CC + k0 + quad * 8];
#pragma unroll
      for (int i = 0; i < 4; ++i)
#pragma unroll
        for (int j = 0; j < 4; ++j)
          acc[i][j] = __builtin_amdgcn_mfma_f32_16x16x32_f16(al[i], bf[j], acc[i][j], 0, 0, 0);
    }
  };

  half8 bfA[4], bfB[4];
  loadB(bfA, 0);
  for (int k0 = 0; k0 < CC; k0 += 64) {
    loadB(bfB, k0 + 32);          // prefetch chunk B
    doK(bfA, k0);                 // compute chunk A (B-load latency hides here)
    if (k0 + 64 < CC) loadB(bfA, k0 + 64);
    doK(bfB, k0 + 32);
  }
  // ---- pooled epilogue ----
  const bool owner = ((l15 & 1) == 0);
  const int colh = l15 >> 1;
  if (w & 1) {
#pragma unroll
    for (int i = 0; i < 4; ++i)
#pragma unroll
      for (int j = 0; j < 4; ++j)
#pragma unroll
        for (int r = 0; r < 4; ++r) {
          float v = acc[i][j][r];
          float o = __shfl_xor(v, 1);
          v = fmaxf(v, o);
          if (owner) Pbuf[w >> 1][i * 16 + quad * 4 + r][j * 8 + colh] = v;
        }
  }
  __syncthreads();
  if (!(w & 1)) {
    const int pr = tile * 2 + (w >> 1);
    unsigned short* phB = (unsigned short*)(phT + ((size_t)b * CM + pr * 32) * C8);
#pragma unroll
    for (int i = 0; i < 4; ++i)
#pragma unroll
      for (int j = 0; j < 4; ++j)
#pragma unroll
        for (int r = 0; r < 4; ++r) {
          float v = acc[i][j][r];
          float o = __shfl_xor(v, 1);
          v = fmaxf(v, o);
          if (owner) {
            const int oc = i * 16 + quad * 4 + r;
            const int col = j * 8 + colh;
            v = fmaxf(v, Pbuf[w >> 1][oc][col]);
            if (isphi)
              phB[(size_t)col * C8 + oc] = f16bits(v);
            else
              gbf[((size_t)b * C2 + (mt - 1) * 64 + oc) * CM + pr * 32 + col] = f2bf(v);
          }
        }
  }
}

// ---------------------------------------------------------------------------
// Fused attention v7 — v4 cooperative structure + RELAXED barrier.
// R4 post-mortem of v6: depth-1 prefetch was defeated because __syncthreads
// lowers to s_waitcnt vmcnt(0) lgkmcnt(0); s_barrier — it drained the
// prefetched global loads every iteration. v7 replaces it with
// barrier_lds_only(): lgkmcnt(0)-only drain + raw s_barrier, so the next
// chunk's gf/pa loads stay in flight across the exchange. Correctness: the
// Pl exchange needs only LDS-write visibility (lgkmcnt) before the barrier;
// in-flight vmcnt loads are wave-private register destinations. Double-buffer
// rewrite hazard unchanged (rewrite of buf at iter+2 fenced by iter+1's
// barrier). grid (64, 8).
// ---------------------------------------------------------------------------
__global__ __launch_bounds__(256, 2)
void attn_v7(const _Float16* __restrict__ thT, const _Float16* __restrict__ phT,
             const unsigned short* __restrict__ gbf,
             unsigned short* __restrict__ attbf) {
  __shared__ __align__(16) unsigned short Pl[2][4][16][40]; // [buf][qs][q][j+pad]
  __shared__ float Dinv[64];
  const int b = blockIdx.y;
  const int q0 = blockIdx.x * 64;
  const int tid = threadIdx.x;
  const int w = tid >> 6, l = tid & 63;
  const int l15 = l & 15, quad = l >> 4;
  // theta B-frags (resident): this wave's query subtile qs == w
  half8 tb[2];
#pragma unroll
  for (int kc = 0; kc < 2; ++kc)
    tb[kc] = *(const half8*)&thT[(size_t)(b * CN + q0 + w * 16 + l15) * C8 +
                                 kc * 32 + quad * 8];
  f32x4 acc[4][4] = {};   // [qs][ct], wave's c2 = w*64 + ct*16 + l15
  float dnp = 0.f;        // numerator partials for qs == w only
  const _Float16* phB = phT + (size_t)b * CM * C8;
  const unsigned short* gB = gbf + (size_t)b * C2 * CM;

  auto loadc = [&](half8 (&pa)[2][2], short8 (&gf)[4], int j0) {
#pragma unroll
    for (int ct = 0; ct < 4; ++ct)
      gf[ct] = *(const short8*)&gB[(size_t)(w * 64 + ct * 16 + l15) * CM +
                                   j0 + quad * 8];
#pragma unroll
    for (int jt = 0; jt < 2; ++jt)
#pragma unroll
      for (int kc = 0; kc < 2; ++kc)
        pa[jt][kc] = *(const half8*)&phB[(size_t)(j0 + jt * 16 + l15) * C8 +
                                         kc * 32 + quad * 8];
  };
  auto step = [&](half8 (&pa)[2][2], short8 (&gf)[4], int buf) {
    // S^T for qs == w, exp, write in PV-A layout.
    f32x4 S0 = {0.f, 0.f, 0.f, 0.f}, S1 = {0.f, 0.f, 0.f, 0.f};
    S0 = __builtin_amdgcn_mfma_f32_16x16x32_f16(pa[0][0], tb[0], S0, 0, 0, 0);
    S0 = __builtin_amdgcn_mfma_f32_16x16x32_f16(pa[0][1], tb[1], S0, 0, 0, 0);
    S1 = __builtin_amdgcn_mfma_f32_16x16x32_f16(pa[1][0], tb[0], S1, 0, 0, 0);
    S1 = __builtin_amdgcn_mfma_f32_16x16x32_f16(pa[1][1], tb[1], S1, 0, 0, 0);
    float e0[4], e1[4];
#pragma unroll
    for (int r = 0; r < 4; ++r) { e0[r] = __expf(S0[r]); e1[r] = __expf(S1[r]); }
    dnp += (e0[0] + e0[1]) + (e0[2] + e0[3]) +
           (e1[0] + e1[1]) + (e1[2] + e1[3]);
    ushort4 w0, w1;
    w0.x = f2bf(e0[0]); w0.y = f2bf(e0[1]); w0.z = f2bf(e0[2]); w0.w = f2bf(e0[3]);
    w1.x = f2bf(e1[0]); w1.y = f2bf(e1[1]); w1.z = f2bf(e1[2]); w1.w = f2bf(e1[3]);
    *(ushort4*)&Pl[buf][w][l15][quad * 4] = w0;
    *(ushort4*)&Pl[buf][w][l15][16 + quad * 4] = w1;
    barrier_lds_only();            // lgkm drain only — vmcnt prefetch survives
    short8 pfrag[4];
#pragma unroll
    for (int qs = 0; qs < 4; ++qs)
      pfrag[qs] = *(const short8*)&Pl[buf][qs][l15][quad * 8];
#pragma unroll
    for (int ct = 0; ct < 4; ++ct)
#pragma unroll
      for (int qs = 0; qs < 4; ++qs)
        acc[qs][ct] = __builtin_amdgcn_mfma_f32_16x16x32_bf16(pfrag[qs], gf[ct],
                                                              acc[qs][ct], 0, 0, 0);
  };

  half8 paA[2][2], paB[2][2];
  short8 gfA[4], gfB[4];
  loadc(paA, gfA, 0);
  for (int j0 = 0; j0 < CM; j0 += 64) {
    loadc(paB, gfB, j0 + 32);           // prefetch chunk B
    step(paA, gfA, 0);                  // chunk A (B's load latency hides here)
    if (j0 + 64 < CM) loadc(paA, gfA, j0 + 64);
    step(paB, gfB, 1);
  }
  // denominators: wave w owns queries qs==w; share via LDS
  float d = dnp;
  d += __shfl_xor(d, 16);
  d += __shfl_xor(d, 32);
  if (quad == 0) Dinv[w * 16 + l15] = 1.0f / d;   // valid for q = l15
  __syncthreads();
  unsigned short* attB = attbf + (size_t)(b * CN + q0) * C2;
#pragma unroll
  for (int qs = 0; qs < 4; ++qs) {
#pragma unroll
    for (int r = 0; r < 4; ++r) {
      const int row = qs * 16 + quad * 4 + r;
      const float iv = Dinv[row];
#pragma unroll
      for (int ct = 0; ct < 4; ++ct)
        attB[(size_t)row * C2 + w * 64 + ct * 16 + l15] =
            f2bf(acc[qs][ct][r] * iv);
    }
  }
}

// ---------------------------------------------------------------------------
// Output projection v4: out = x + gamma * (Wo @ att).
// R4 post-mortem of v3: VGPR_Count stayed 32 — the scheduler SANK the
// "up-front" loads back to their consumers, so MLP never materialized and
// duration was unchanged (69.6 us, 1.58 TB/s, latency-bound).
// v4 pins the schedule: 32 fragment loads, then sched_barrier(0) (no
// instruction may cross), then the 32 MFMAs. Forces ~32 loads in flight
// per lane (32 KB/wave). launch_bounds(256,2) legalizes ~200 VGPRs; the
// occupancy drop (65% -> ~25%) is intended: MLP replaces TLP.
// Grid (64, 8, 8).
// ---------------------------------------------------------------------------
__global__ __launch_bounds__(256, 2)
void oproj_v4(const unsigned short* __restrict__ woh,
              const unsigned short* __restrict__ attbf,
              const float* __restrict__ X, const float* __restrict__ gamma,
              float* __restrict__ out) {
  __shared__ __align__(16) float Tw[2][4][16][34];  // [i][wave][c][n+pad]
  const int b = blockIdx.z;
  const int mt = blockIdx.y;
  const int n0 = blockIdx.x * 64;
  const int tid = threadIdx.x;
  const int w = tid >> 6, l = tid & 63;
  const int l15 = l & 15, quad = l >> 4;
  const int wc = w >> 1, wn = w & 1;             // wave -> (c-half, n-half)
  const int cbase = mt * 64 + wc * 32;
  const int nbase = n0 + wn * 32;
  const unsigned short* Bb = attbf + (size_t)b * CN * C2;
  // All fragments up-front: 32 independent global loads per lane.
  short8 a[8][2], bb[8][2];
#pragma unroll
  for (int ks = 0; ks < 8; ++ks) {
#pragma unroll
    for (int i = 0; i < 2; ++i)
      a[ks][i] = *(const short8*)&woh[(size_t)(cbase + i * 16 + l15) * C2 +
                                      ks * 32 + quad * 8];
#pragma unroll
    for (int j = 0; j < 2; ++j)
      bb[ks][j] = *(const short8*)&Bb[(size_t)(nbase + j * 16 + l15) * C2 +
                                      ks * 32 + quad * 8];
  }
  __builtin_amdgcn_sched_barrier(0);   // loads may NOT sink past this point
  f32x4 acc[2][2] = {};
#pragma unroll
  for (int ks = 0; ks < 8; ++ks)
#pragma unroll
    for (int i = 0; i < 2; ++i)
#pragma unroll
      for (int j = 0; j < 2; ++j)
        acc[i][j] = __builtin_amdgcn_mfma_f32_16x16x32_bf16(a[ks][i], bb[ks][j],
                                                            acc[i][j], 0, 0, 0);
  const float gm = gamma[0];
  // acc[i][j][r] lives at (c = i*16 + quad*4 + r, n = j*16 + l15).
  const int cp = l >> 2;            // reader's c-row within 16
  const int nq = (l & 3) * 8;       // reader's n-offset (8 floats)
#pragma unroll
  for (int i = 0; i < 2; ++i)
#pragma unroll
    for (int j = 0; j < 2; ++j)
#pragma unroll
      for (int r = 0; r < 4; ++r)
        Tw[i][w][quad * 4 + r][j * 16 + l15] = acc[i][j][r];
#pragma unroll
  for (int i = 0; i < 2; ++i) {
    const float4 v0 = *(const float4*)&Tw[i][w][cp][nq];
    const float4 v1 = *(const float4*)&Tw[i][w][cp][nq + 4];
    const int c = cbase + i * 16 + cp;
    const size_t idx = ((size_t)b * CC + c) * CN + nbase + nq;
    const float4 x0 = *(const float4*)&X[idx];
    const float4 x1 = *(const float4*)&X[idx + 4];
    float4 o0, o1;
    o0.x = x0.x + gm * v0.x; o0.y = x0.y + gm * v0.y;
    o0.z = x0.z + gm * v0.z; o0.w = x0.w + gm * v0.w;
    o1.x = x1.x + gm * v1.x; o1.y = x1.y + gm * v1.y;
    o1.z = x1.z + gm * v1.z; o1.w = x1.w + gm * v1.w;
    *(float4*)&out[idx] = o0;
    *(float4*)&out[idx + 4] = o1;
  }
}

// ---------------------------------------------------------------------------
extern "C" void kernel_launch(void* const* d_in, const int* in_sizes, int n_in,
                              void* d_out, int out_size, void* d_ws, size_t ws_size,
                              hipStream_t stream) {
  const float* x       = (const float*)d_in[0];
  const float* w_theta = (const float*)d_in[1];
  const float* w_phi   = (const float*)d_in[2];
  const float* w_g     = (const float*)d_in[3];
  const float* w_o     = (const float*)d_in[4];
  const float* gamma   = (const float*)d_in[5];
  float* out = (float*)d_out;
  char* wsb = (char*)d_ws;

  // Workspace layout (bytes), total 43,778,048:
  _Float16*       xT    = (_Float16*)(wsb + 0);          // 32 MiB [B,4096,512]
  _Float16*       thT   = (_Float16*)(wsb + 33554432);   //  4 MiB [B,4096,64]
  _Float16*       phT   = (_Float16*)(wsb + 37748736);   //  1 MiB [B,1024,64]
  unsigned short* gbf   = (unsigned short*)(wsb + 38797312); // 4 MiB [B,256,1024]
  _Float16*       wth   = (_Float16*)(wsb + 42991616);
  _Float16*       wtl   = (_Float16*)(wsb + 43057152);
  _Float16*       wph   = (_Float16*)(wsb + 43122688);
  _Float16*       wpl   = (_Float16*)(wsb + 43188224);
  _Float16*       wgf   = (_Float16*)(wsb + 43253760);
  unsigned short* woh   = (unsigned short*)(wsb + 43515904);
  unsigned short* attbf = (unsigned short*)(wsb + 0);    // 16 MiB, aliases xT (dead)

  dim3 blk(256);
  conv_w<<<512, blk, 0, stream>>>(w_theta, w_phi, w_g, w_o,
                                  wth, wtl, wph, wpl, wgf, woh);
  xpose<<<dim3(64, 8, CB), blk, 0, stream>>>(x, xT);
  proj_th2<<<dim3(128, CB), blk, 0, stream>>>(wth, wtl, xT, thT);
  proj_pg<<<dim3(16, 5, CB), blk, 0, stream>>>(wph, wpl, wgf, xT, phT, gbf);
  attn_v7<<<dim3(64, CB), blk, 0, stream>>>(thT, phT, gbf, attbf);
  oproj_v4<<<dim3(64, 8, CB), blk, 0, stream>>>(woh, attbf, x, gamma, out);
}

// Round 9
// 312.527 us; speedup vs baseline: 1.1081x; 1.1081x over previous
//
#include <hip/hip_runtime.h>
#include <math.h>

// Problem constants (B=8, C=512, H=W=64)
constexpr int CB = 8;
constexpr int CC = 512;
constexpr int CN = 4096;   // H*W
constexpr int CM = 1024;   // pooled positions
constexpr int C8 = 64;     // C/8
constexpr int C2 = 256;    // C/2

typedef __attribute__((ext_vector_type(8))) short short8;
typedef __attribute__((ext_vector_type(8))) _Float16 half8;
typedef __attribute__((ext_vector_type(4))) float f32x4;

__device__ inline unsigned short f2bf(float f) {
  unsigned int u = __float_as_uint(f);
  return (unsigned short)((u + 0x7FFFu + ((u >> 16) & 1u)) >> 16);
}
__device__ inline unsigned short f16bits(float f) {
  union { _Float16 h; unsigned short u; } c;
  c.h = (_Float16)f;
  return c.u;
}

// Relaxed workgroup barrier: drains LDS ops only (lgkmcnt), NOT the vmcnt
// queue — prefetched global loads stay in flight across it.
__device__ inline void barrier_lds_only() {
  asm volatile("s_waitcnt lgkmcnt(0)" ::: "memory");
  __builtin_amdgcn_s_barrier();
  asm volatile("" ::: "memory");
}

// ---------------------------------------------------------------------------
// Weight conversion: theta/phi -> f16 hi/lo (2-term), g -> f16, o -> bf16.
// ---------------------------------------------------------------------------
__global__ __launch_bounds__(256)
void conv_w(const float* __restrict__ wt, const float* __restrict__ wp,
            const float* __restrict__ wg, const float* __restrict__ wo,
            _Float16* __restrict__ wth, _Float16* __restrict__ wtl,
            _Float16* __restrict__ wph, _Float16* __restrict__ wpl,
            _Float16* __restrict__ wgf, unsigned short* __restrict__ woh) {
  const int i = blockIdx.x * 256 + threadIdx.x;
  if (i < 32768) {
    float a = wt[i];
    _Float16 h = (_Float16)a;
    wth[i] = h; wtl[i] = (_Float16)(a - (float)h);
    a = wp[i];
    h = (_Float16)a;
    wph[i] = h; wpl[i] = (_Float16)(a - (float)h);
  }
  wgf[i] = (_Float16)wg[i];
  woh[i] = f2bf(wo[i]);
}

// ---------------------------------------------------------------------------
// Transpose+convert: x fp32 [b][c][n] -> xT f16 [b][n][c].
// grid (64 n-tiles, 8 c-tiles, 8 b), 64x64 tiles.
// ---------------------------------------------------------------------------
__global__ __launch_bounds__(256)
void xpose(const float* __restrict__ X, _Float16* __restrict__ xT) {
  __shared__ __align__(16) float raw[64][68];
  const int b = blockIdx.z, c0 = blockIdx.y * 64, n0 = blockIdx.x * 64;
  const float* Xb = X + ((size_t)b * CC + c0) * CN + n0;
  const int tid = threadIdx.x;
#pragma unroll
  for (int it = 0; it < 4; ++it) {
    const int idx = it * 256 + tid;
    const int row = idx >> 4, col4 = (idx & 15) * 4;
    *(float4*)&raw[row][col4] = *(const float4*)&Xb[(size_t)row * CN + col4];
  }
  __syncthreads();
  unsigned short* Yb = (unsigned short*)(xT + ((size_t)b * CN + n0) * CC + c0);
#pragma unroll
  for (int it = 0; it < 4; ++it) {
    const int idx = it * 256 + tid;
    const int n = idx >> 4, c4 = (idx & 15) * 4;
    ushort4 o;
    o.x = f16bits(raw[c4 + 0][n]);
    o.y = f16bits(raw[c4 + 1][n]);
    o.z = f16bits(raw[c4 + 2][n]);
    o.w = f16bits(raw[c4 + 3][n]);
    *(ushort4*)&Yb[(size_t)n * CC + c4] = o;
  }
}

// ---------------------------------------------------------------------------
// theta projection v2: all 16 B-fragments up-front, weights streamed (L2-hot
// across 1024 blocks). Output thT[b][pos][64] f16 via LDS transpose.
// grid (128, 8).
// ---------------------------------------------------------------------------
__global__ __launch_bounds__(256, 2)
void proj_th2(const _Float16* __restrict__ Wh, const _Float16* __restrict__ Wl,
              const _Float16* __restrict__ xT, _Float16* __restrict__ thT) {
  __shared__ __align__(16) unsigned short LT[32][68];
  const int b = blockIdx.y, n0 = blockIdx.x * 32;
  const int tid = threadIdx.x;
  const int w = tid >> 6, l = tid & 63;
  const int l15 = l & 15, quad = l >> 4;
  const int wn = w & 1, wo = w >> 1;   // wave -> (n-half, oc-half)
  const _Float16* Brow = xT + (size_t)(b * CN + n0 + wn * 16 + l15) * CC;
  half8 bfr[16];
#pragma unroll
  for (int kk = 0; kk < 16; ++kk)
    bfr[kk] = *(const half8*)&Brow[kk * 32 + quad * 8];
  __builtin_amdgcn_sched_barrier(0);   // pin: all B loads issued before MFMAs
  f32x4 acc[2] = {};
#pragma unroll
  for (int kk = 0; kk < 16; ++kk) {
    const int k0 = kk * 32;
#pragma unroll
    for (int i = 0; i < 2; ++i) {
      const half8 ah = *(const half8*)&Wh[(size_t)(wo * 32 + i * 16 + l15) * CC +
                                          k0 + quad * 8];
      const half8 al = *(const half8*)&Wl[(size_t)(wo * 32 + i * 16 + l15) * CC +
                                          k0 + quad * 8];
      acc[i] = __builtin_amdgcn_mfma_f32_16x16x32_f16(ah, bfr[kk], acc[i], 0, 0, 0);
      acc[i] = __builtin_amdgcn_mfma_f32_16x16x32_f16(al, bfr[kk], acc[i], 0, 0, 0);
    }
  }
  // epilogue: LT[n][oc], n = col = l15, oc = A-row
#pragma unroll
  for (int i = 0; i < 2; ++i)
#pragma unroll
    for (int r = 0; r < 4; ++r)
      LT[wn * 16 + l15][wo * 32 + i * 16 + quad * 4 + r] = f16bits(acc[i][r]);
  __syncthreads();
  unsigned short* Yb = (unsigned short*)(thT + (size_t)(b * CN + n0) * C8);
#pragma unroll
  for (int it = 0; it < 2; ++it) {
    const int idx = it * 256 + tid;
    const int pos = idx >> 4, c4 = (idx & 15) * 4;
    ushort4 v = *(const ushort4*)&LT[pos][c4];
    *(ushort4*)&Yb[(size_t)pos * C8 + c4] = v;
  }
}

// ---------------------------------------------------------------------------
// phi + g projections with FUSED 2x2 maxpool epilogue.
// Depth-1 pipeline on B (xT) fragments. grid (16, 5, 8).
// ---------------------------------------------------------------------------
__global__ __launch_bounds__(256)
void proj_pg(const _Float16* __restrict__ Wph, const _Float16* __restrict__ Wpl,
             const _Float16* __restrict__ Wg, const _Float16* __restrict__ xT,
             _Float16* __restrict__ phT, unsigned short* __restrict__ gbf) {
  __shared__ float Pbuf[2][64][33];
  const int b = blockIdx.z, mt = blockIdx.y, tile = blockIdx.x;
  const int n0 = tile * 256;
  const int tid = threadIdx.x;
  const int w = tid >> 6, l = tid & 63;
  const int l15 = l & 15, quad = l >> 4;
  const bool isphi = (mt == 0);
  const _Float16* Ah = isphi ? Wph : (Wg + (size_t)(mt - 1) * 64 * CC);
  f32x4 acc[4][4] = {};
  const _Float16* Bbase = xT + (size_t)(b * CN + n0 + w * 64) * CC;

  auto loadB = [&](half8 (&bf)[4], int k0) {
#pragma unroll
    for (int j = 0; j < 4; ++j)
      bf[j] = *(const half8*)&Bbase[(size_t)(j * 16 + l15) * CC + k0 + quad * 8];
  };
  auto doK = [&](half8 (&bf)[4], int k0) {
    half8 ah[4];
#pragma unroll
    for (int i = 0; i < 4; ++i)
      ah[i] = *(const half8*)&Ah[(size_t)(i * 16 + l15) * CC + k0 + quad * 8];
#pragma unroll
    for (int i = 0; i < 4; ++i)
#pragma unroll
      for (int j = 0; j < 4; ++j)
        acc[i][j] = __builtin_amdgcn_mfma_f32_16x16x32_f16(ah[i], bf[j], acc[i][j], 0, 0, 0);
    if (isphi) {
      half8 al[4];
#pragma unroll
      for (int i = 0; i < 4; ++i)
        al[i] = *(const half8*)&Wpl[(size_t)(i * 16 + l15) * CC + k0 + quad * 8];
#pragma unroll
      for (int i = 0; i < 4; ++i)
#pragma unroll
        for (int j = 0; j < 4; ++j)
          acc[i][j] = __builtin_amdgcn_mfma_f32_16x16x32_f16(al[i], bf[j], acc[i][j], 0, 0, 0);
    }
  };

  half8 bfA[4], bfB[4];
  loadB(bfA, 0);
  for (int k0 = 0; k0 < CC; k0 += 64) {
    loadB(bfB, k0 + 32);          // prefetch chunk B
    doK(bfA, k0);                 // compute chunk A (B-load latency hides here)
    if (k0 + 64 < CC) loadB(bfA, k0 + 64);
    doK(bfB, k0 + 32);
  }
  // ---- pooled epilogue ----
  const bool owner = ((l15 & 1) == 0);
  const int colh = l15 >> 1;
  if (w & 1) {
#pragma unroll
    for (int i = 0; i < 4; ++i)
#pragma unroll
      for (int j = 0; j < 4; ++j)
#pragma unroll
        for (int r = 0; r < 4; ++r) {
          float v = acc[i][j][r];
          float o = __shfl_xor(v, 1);
          v = fmaxf(v, o);
          if (owner) Pbuf[w >> 1][i * 16 + quad * 4 + r][j * 8 + colh] = v;
        }
  }
  __syncthreads();
  if (!(w & 1)) {
    const int pr = tile * 2 + (w >> 1);
    unsigned short* phB = (unsigned short*)(phT + ((size_t)b * CM + pr * 32) * C8);
#pragma unroll
    for (int i = 0; i < 4; ++i)
#pragma unroll
      for (int j = 0; j < 4; ++j)
#pragma unroll
        for (int r = 0; r < 4; ++r) {
          float v = acc[i][j][r];
          float o = __shfl_xor(v, 1);
          v = fmaxf(v, o);
          if (owner) {
            const int oc = i * 16 + quad * 4 + r;
            const int col = j * 8 + colh;
            v = fmaxf(v, Pbuf[w >> 1][oc][col]);
            if (isphi)
              phB[(size_t)col * C8 + oc] = f16bits(v);
            else
              gbf[((size_t)b * C2 + (mt - 1) * 64 + oc) * CM + pr * 32 + col] = f2bf(v);
          }
        }
  }
}

// ---------------------------------------------------------------------------
// Fused attention v7 — v4 cooperative structure + relaxed barrier.
// (R5: relaxed barrier measured NULL vs v6 — kept because harmless; attn
// will be restructured with LDS staging next round if oproj_v5 validates.)
// grid (64, 8).
// ---------------------------------------------------------------------------
__global__ __launch_bounds__(256, 2)
void attn_v7(const _Float16* __restrict__ thT, const _Float16* __restrict__ phT,
             const unsigned short* __restrict__ gbf,
             unsigned short* __restrict__ attbf) {
  __shared__ __align__(16) unsigned short Pl[2][4][16][40]; // [buf][qs][q][j+pad]
  __shared__ float Dinv[64];
  const int b = blockIdx.y;
  const int q0 = blockIdx.x * 64;
  const int tid = threadIdx.x;
  const int w = tid >> 6, l = tid & 63;
  const int l15 = l & 15, quad = l >> 4;
  half8 tb[2];
#pragma unroll
  for (int kc = 0; kc < 2; ++kc)
    tb[kc] = *(const half8*)&thT[(size_t)(b * CN + q0 + w * 16 + l15) * C8 +
                                 kc * 32 + quad * 8];
  f32x4 acc[4][4] = {};   // [qs][ct], wave's c2 = w*64 + ct*16 + l15
  float dnp = 0.f;        // numerator partials for qs == w only
  const _Float16* phB = phT + (size_t)b * CM * C8;
  const unsigned short* gB = gbf + (size_t)b * C2 * CM;

  auto loadc = [&](half8 (&pa)[2][2], short8 (&gf)[4], int j0) {
#pragma unroll
    for (int ct = 0; ct < 4; ++ct)
      gf[ct] = *(const short8*)&gB[(size_t)(w * 64 + ct * 16 + l15) * CM +
                                   j0 + quad * 8];
#pragma unroll
    for (int jt = 0; jt < 2; ++jt)
#pragma unroll
      for (int kc = 0; kc < 2; ++kc)
        pa[jt][kc] = *(const half8*)&phB[(size_t)(j0 + jt * 16 + l15) * C8 +
                                         kc * 32 + quad * 8];
  };
  auto step = [&](half8 (&pa)[2][2], short8 (&gf)[4], int buf) {
    f32x4 S0 = {0.f, 0.f, 0.f, 0.f}, S1 = {0.f, 0.f, 0.f, 0.f};
    S0 = __builtin_amdgcn_mfma_f32_16x16x32_f16(pa[0][0], tb[0], S0, 0, 0, 0);
    S0 = __builtin_amdgcn_mfma_f32_16x16x32_f16(pa[0][1], tb[1], S0, 0, 0, 0);
    S1 = __builtin_amdgcn_mfma_f32_16x16x32_f16(pa[1][0], tb[0], S1, 0, 0, 0);
    S1 = __builtin_amdgcn_mfma_f32_16x16x32_f16(pa[1][1], tb[1], S1, 0, 0, 0);
    float e0[4], e1[4];
#pragma unroll
    for (int r = 0; r < 4; ++r) { e0[r] = __expf(S0[r]); e1[r] = __expf(S1[r]); }
    dnp += (e0[0] + e0[1]) + (e0[2] + e0[3]) +
           (e1[0] + e1[1]) + (e1[2] + e1[3]);
    ushort4 w0, w1;
    w0.x = f2bf(e0[0]); w0.y = f2bf(e0[1]); w0.z = f2bf(e0[2]); w0.w = f2bf(e0[3]);
    w1.x = f2bf(e1[0]); w1.y = f2bf(e1[1]); w1.z = f2bf(e1[2]); w1.w = f2bf(e1[3]);
    *(ushort4*)&Pl[buf][w][l15][quad * 4] = w0;
    *(ushort4*)&Pl[buf][w][l15][16 + quad * 4] = w1;
    barrier_lds_only();
    short8 pfrag[4];
#pragma unroll
    for (int qs = 0; qs < 4; ++qs)
      pfrag[qs] = *(const short8*)&Pl[buf][qs][l15][quad * 8];
#pragma unroll
    for (int ct = 0; ct < 4; ++ct)
#pragma unroll
      for (int qs = 0; qs < 4; ++qs)
        acc[qs][ct] = __builtin_amdgcn_mfma_f32_16x16x32_bf16(pfrag[qs], gf[ct],
                                                              acc[qs][ct], 0, 0, 0);
  };

  half8 paA[2][2], paB[2][2];
  short8 gfA[4], gfB[4];
  loadc(paA, gfA, 0);
  for (int j0 = 0; j0 < CM; j0 += 64) {
    loadc(paB, gfB, j0 + 32);
    step(paA, gfA, 0);
    if (j0 + 64 < CM) loadc(paA, gfA, j0 + 64);
    step(paB, gfB, 1);
  }
  float d = dnp;
  d += __shfl_xor(d, 16);
  d += __shfl_xor(d, 32);
  if (quad == 0) Dinv[w * 16 + l15] = 1.0f / d;   // valid for q = l15
  __syncthreads();
  unsigned short* attB = attbf + (size_t)(b * CN + q0) * C2;
#pragma unroll
  for (int qs = 0; qs < 4; ++qs) {
#pragma unroll
    for (int r = 0; r < 4; ++r) {
      const int row = qs * 16 + quad * 4 + r;
      const float iv = Dinv[row];
#pragma unroll
      for (int ct = 0; ct < 4; ++ct)
        attB[(size_t)row * C2 + w * 64 + ct * 16 + l15] =
            f2bf(acc[qs][ct][r] * iv);
    }
  }
}

// ---------------------------------------------------------------------------
// Output projection v5 — LDS-STAGED GEMM (m97-family recipe, reg-staged).
// R5 post-mortem: v2/v3/v4 (direct scattered fragment loads) all pinned at
// ~69 us / 1.6 TB/s / ~650 cyc-per-load-serialized regardless of occupancy
// and VGPR. Diagnosis: every fragment load's 64 lanes scatter over 16 rows
// x 64 B chunks (512 B stride) — the anti-pattern. v5 stages the FULL
// K=256 A-tile (Wo 64x256) and B-tile (attbf 64x256) into LDS with
// contiguous 512 B-per-row global reads (16 independent uint4 loads/thread
// = real MLP), rows XOR-swizzled (slot ^= row&7, write AND read sides) so
// stride-512B ds_read_b128 fragments are ~2-way (free, m136). Then 8x4
// MFMAs from LDS (no K-loop staging — K fits), then the proven Tw
// transpose epilogue (overlaid on the staging LDS after a barrier).
// LDS = 64 KiB exactly -> 2 blocks/CU. Grid (64, 8, 8).
// ---------------------------------------------------------------------------
__global__ __launch_bounds__(256, 2)
void oproj_v5(const unsigned short* __restrict__ woh,
              const unsigned short* __restrict__ attbf,
              const float* __restrict__ X, const float* __restrict__ gamma,
              float* __restrict__ out) {
  __shared__ __align__(16) unsigned short smem[2 * 64 * 256];  // 64 KiB
  unsigned short* As = smem;             // [64][256] shorts, XOR-swizzled rows
  unsigned short* Bs = smem + 64 * 256;  // [64][256]
  float* Twf = (float*)smem;             // epilogue overlay [2][4][16][36]
  const int b = blockIdx.z, mt = blockIdx.y, n0 = blockIdx.x * 64;
  const int tid = threadIdx.x;
  const int w = tid >> 6, l = tid & 63;
  const int l15 = l & 15, quad = l >> 4;
  const int wc = w >> 1, wn = w & 1;     // wave -> (c-half, n-half)

  // ---- stage A (Wo rows mt*64..+63) and B (attbf rows n0..+63), K=256 ----
  const unsigned short* Asrc = woh + (size_t)(mt * 64) * C2;
  const unsigned short* Bsrc = attbf + ((size_t)b * CN + n0) * C2;
  uint4 ra[8], rb[8];
#pragma unroll
  for (int s = 0; s < 8; ++s) {
    const int idx = s * 256 + tid;       // 0..2047 over 64 rows x 32 slots
    const int row = idx >> 5, sl = idx & 31;
    ra[s] = *(const uint4*)&Asrc[(size_t)row * C2 + sl * 8];
    rb[s] = *(const uint4*)&Bsrc[(size_t)row * C2 + sl * 8];
  }
  __builtin_amdgcn_sched_barrier(0);     // keep all 16 loads issued up-front
#pragma unroll
  for (int s = 0; s < 8; ++s) {
    const int idx = s * 256 + tid;
    const int row = idx >> 5, sl = idx & 31;
    const int sw = sl ^ (row & 7);       // XOR-swizzle (write side)
    *(uint4*)&As[row * 256 + sw * 8] = ra[s];
    *(uint4*)&Bs[row * 256 + sw * 8] = rb[s];
  }
  __syncthreads();

  // ---- MFMA phase: acc[2][2] per wave over its 32x32 quadrant ----
  f32x4 acc[2][2] = {};
#pragma unroll
  for (int kk = 0; kk < 8; ++kk) {
    const int sbase = kk * 4 + quad;     // slot = k0/8 + quad (pre-swizzle)
    short8 af[2], bf[2];
#pragma unroll
    for (int i = 0; i < 2; ++i) {
      const int row = wc * 32 + i * 16 + l15;
      af[i] = *(const short8*)&As[row * 256 + ((sbase ^ (row & 7)) * 8)];
    }
#pragma unroll
    for (int j = 0; j < 2; ++j) {
      const int row = wn * 32 + j * 16 + l15;
      bf[j] = *(const short8*)&Bs[row * 256 + ((sbase ^ (row & 7)) * 8)];
    }
#pragma unroll
    for (int i = 0; i < 2; ++i)
#pragma unroll
      for (int j = 0; j < 2; ++j)
        acc[i][j] = __builtin_amdgcn_mfma_f32_16x16x32_bf16(af[i], bf[j],
                                                            acc[i][j], 0, 0, 0);
  }
  __syncthreads();   // all waves' LDS reads done before Tw overlay writes

  // ---- epilogue: wave-local Tw transpose, float4 X+out streaming ----
  const float gm = gamma[0];
  const int cp = l >> 2, nq = (l & 3) * 8;
  // Tw layout: ((i*4 + w)*16 + r)*36 + col  (pad 36 -> 16B-aligned rows)
#pragma unroll
  for (int i = 0; i < 2; ++i)
#pragma unroll
    for (int j = 0; j < 2; ++j)
#pragma unroll
      for (int r = 0; r < 4; ++r)
        Twf[((i * 4 + w) * 16 + quad * 4 + r) * 36 + j * 16 + l15] = acc[i][j][r];
#pragma unroll
  for (int i = 0; i < 2; ++i) {
    const float4 v0 = *(const float4*)&Twf[((i * 4 + w) * 16 + cp) * 36 + nq];
    const float4 v1 = *(const float4*)&Twf[((i * 4 + w) * 16 + cp) * 36 + nq + 4];
    const int c = mt * 64 + wc * 32 + i * 16 + cp;
    const size_t idx = ((size_t)b * CC + c) * CN + n0 + wn * 32 + nq;
    const float4 x0 = *(const float4*)&X[idx];
    const float4 x1 = *(const float4*)&X[idx + 4];
    float4 o0, o1;
    o0.x = x0.x + gm * v0.x; o0.y = x0.y + gm * v0.y;
    o0.z = x0.z + gm * v0.z; o0.w = x0.w + gm * v0.w;
    o1.x = x1.x + gm * v1.x; o1.y = x1.y + gm * v1.y;
    o1.z = x1.z + gm * v1.z; o1.w = x1.w + gm * v1.w;
    *(float4*)&out[idx] = o0;
    *(float4*)&out[idx + 4] = o1;
  }
}

// ---------------------------------------------------------------------------
extern "C" void kernel_launch(void* const* d_in, const int* in_sizes, int n_in,
                              void* d_out, int out_size, void* d_ws, size_t ws_size,
                              hipStream_t stream) {
  const float* x       = (const float*)d_in[0];
  const float* w_theta = (const float*)d_in[1];
  const float* w_phi   = (const float*)d_in[2];
  const float* w_g     = (const float*)d_in[3];
  const float* w_o     = (const float*)d_in[4];
  const float* gamma   = (const float*)d_in[5];
  float* out = (float*)d_out;
  char* wsb = (char*)d_ws;

  // Workspace layout (bytes), total 43,778,048:
  _Float16*       xT    = (_Float16*)(wsb + 0);          // 32 MiB [B,4096,512]
  _Float16*       thT   = (_Float16*)(wsb + 33554432);   //  4 MiB [B,4096,64]
  _Float16*       phT   = (_Float16*)(wsb + 37748736);   //  1 MiB [B,1024,64]
  unsigned short* gbf   = (unsigned short*)(wsb + 38797312); // 4 MiB [B,256,1024]
  _Float16*       wth   = (_Float16*)(wsb + 42991616);
  _Float16*       wtl   = (_Float16*)(wsb + 43057152);
  _Float16*       wph   = (_Float16*)(wsb + 43122688);
  _Float16*       wpl   = (_Float16*)(wsb + 43188224);
  _Float16*       wgf   = (_Float16*)(wsb + 43253760);
  unsigned short* woh   = (unsigned short*)(wsb + 43515904);
  unsigned short* attbf = (unsigned short*)(wsb + 0);    // 16 MiB, aliases xT (dead)

  dim3 blk(256);
  conv_w<<<512, blk, 0, stream>>>(w_theta, w_phi, w_g, w_o,
                                  wth, wtl, wph, wpl, wgf, woh);
  xpose<<<dim3(64, 8, CB), blk, 0, stream>>>(x, xT);
  proj_th2<<<dim3(128, CB), blk, 0, stream>>>(wth, wtl, xT, thT);
  proj_pg<<<dim3(16, 5, CB), blk, 0, stream>>>(wph, wpl, wgf, xT, phT, gbf);
  attn_v7<<<dim3(64, CB), blk, 0, stream>>>(thT, phT, gbf, attbf);
  oproj_v5<<<dim3(64, 8, CB), blk, 0, stream>>>(woh, attbf, x, gamma, out);
}

// Round 11
// 285.256 us; speedup vs baseline: 1.2140x; 1.0956x over previous
//
#include <hip/hip_runtime.h>
#include <math.h>

// Problem constants (B=8, C=512, H=W=64)
constexpr int CB = 8;
constexpr int CC = 512;
constexpr int CN = 4096;   // H*W
constexpr int CM = 1024;   // pooled positions
constexpr int C8 = 64;     // C/8
constexpr int C2 = 256;    // C/2

typedef __attribute__((ext_vector_type(8))) short short8;
typedef __attribute__((ext_vector_type(8))) _Float16 half8;
typedef __attribute__((ext_vector_type(4))) float f32x4;

__device__ inline unsigned short f2bf(float f) {
  unsigned int u = __float_as_uint(f);
  return (unsigned short)((u + 0x7FFFu + ((u >> 16) & 1u)) >> 16);
}
__device__ inline unsigned short f16bits(float f) {
  union { _Float16 h; unsigned short u; } c;
  c.h = (_Float16)f;
  return c.u;
}

// Relaxed workgroup barrier: drains LDS ops only (lgkmcnt), NOT the vmcnt
// queue — prefetched global loads stay in flight across it.
__device__ inline void barrier_lds_only() {
  asm volatile("s_waitcnt lgkmcnt(0)" ::: "memory");
  __builtin_amdgcn_s_barrier();
  asm volatile("" ::: "memory");
}

// ---------------------------------------------------------------------------
// Weight conversion: theta/phi -> f16 hi/lo (2-term), g -> f16, o -> bf16.
// ---------------------------------------------------------------------------
__global__ __launch_bounds__(256)
void conv_w(const float* __restrict__ wt, const float* __restrict__ wp,
            const float* __restrict__ wg, const float* __restrict__ wo,
            _Float16* __restrict__ wth, _Float16* __restrict__ wtl,
            _Float16* __restrict__ wph, _Float16* __restrict__ wpl,
            _Float16* __restrict__ wgf, unsigned short* __restrict__ woh) {
  const int i = blockIdx.x * 256 + threadIdx.x;
  if (i < 32768) {
    float a = wt[i];
    _Float16 h = (_Float16)a;
    wth[i] = h; wtl[i] = (_Float16)(a - (float)h);
    a = wp[i];
    h = (_Float16)a;
    wph[i] = h; wpl[i] = (_Float16)(a - (float)h);
  }
  wgf[i] = (_Float16)wg[i];
  woh[i] = f2bf(wo[i]);
}

// ---------------------------------------------------------------------------
// Transpose+convert: x fp32 [b][c][n] -> xT f16 [b][n][c].
// grid (64 n-tiles, 8 c-tiles, 8 b), 64x64 tiles.
// ---------------------------------------------------------------------------
__global__ __launch_bounds__(256)
void xpose(const float* __restrict__ X, _Float16* __restrict__ xT) {
  __shared__ __align__(16) float raw[64][68];
  const int b = blockIdx.z, c0 = blockIdx.y * 64, n0 = blockIdx.x * 64;
  const float* Xb = X + ((size_t)b * CC + c0) * CN + n0;
  const int tid = threadIdx.x;
#pragma unroll
  for (int it = 0; it < 4; ++it) {
    const int idx = it * 256 + tid;
    const int row = idx >> 4, col4 = (idx & 15) * 4;
    *(float4*)&raw[row][col4] = *(const float4*)&Xb[(size_t)row * CN + col4];
  }
  __syncthreads();
  unsigned short* Yb = (unsigned short*)(xT + ((size_t)b * CN + n0) * CC + c0);
#pragma unroll
  for (int it = 0; it < 4; ++it) {
    const int idx = it * 256 + tid;
    const int n = idx >> 4, c4 = (idx & 15) * 4;
    ushort4 o;
    o.x = f16bits(raw[c4 + 0][n]);
    o.y = f16bits(raw[c4 + 1][n]);
    o.z = f16bits(raw[c4 + 2][n]);
    o.w = f16bits(raw[c4 + 3][n]);
    *(ushort4*)&Yb[(size_t)n * CC + c4] = o;
  }
}

// ---------------------------------------------------------------------------
// theta projection v2: all 16 B-fragments up-front, weights streamed (L2-hot
// across 1024 blocks). Output thT[b][pos][64] f16 via LDS transpose.
// grid (128, 8).
// ---------------------------------------------------------------------------
__global__ __launch_bounds__(256, 2)
void proj_th2(const _Float16* __restrict__ Wh, const _Float16* __restrict__ Wl,
              const _Float16* __restrict__ xT, _Float16* __restrict__ thT) {
  __shared__ __align__(16) unsigned short LT[32][68];
  const int b = blockIdx.y, n0 = blockIdx.x * 32;
  const int tid = threadIdx.x;
  const int w = tid >> 6, l = tid & 63;
  const int l15 = l & 15, quad = l >> 4;
  const int wn = w & 1, wo = w >> 1;   // wave -> (n-half, oc-half)
  const _Float16* Brow = xT + (size_t)(b * CN + n0 + wn * 16 + l15) * CC;
  half8 bfr[16];
#pragma unroll
  for (int kk = 0; kk < 16; ++kk)
    bfr[kk] = *(const half8*)&Brow[kk * 32 + quad * 8];
  __builtin_amdgcn_sched_barrier(0);   // pin: all B loads issued before MFMAs
  f32x4 acc[2] = {};
#pragma unroll
  for (int kk = 0; kk < 16; ++kk) {
    const int k0 = kk * 32;
#pragma unroll
    for (int i = 0; i < 2; ++i) {
      const half8 ah = *(const half8*)&Wh[(size_t)(wo * 32 + i * 16 + l15) * CC +
                                          k0 + quad * 8];
      const half8 al = *(const half8*)&Wl[(size_t)(wo * 32 + i * 16 + l15) * CC +
                                          k0 + quad * 8];
      acc[i] = __builtin_amdgcn_mfma_f32_16x16x32_f16(ah, bfr[kk], acc[i], 0, 0, 0);
      acc[i] = __builtin_amdgcn_mfma_f32_16x16x32_f16(al, bfr[kk], acc[i], 0, 0, 0);
    }
  }
  // epilogue: LT[n][oc], n = col = l15, oc = A-row
#pragma unroll
  for (int i = 0; i < 2; ++i)
#pragma unroll
    for (int r = 0; r < 4; ++r)
      LT[wn * 16 + l15][wo * 32 + i * 16 + quad * 4 + r] = f16bits(acc[i][r]);
  __syncthreads();
  unsigned short* Yb = (unsigned short*)(thT + (size_t)(b * CN + n0) * C8);
#pragma unroll
  for (int it = 0; it < 2; ++it) {
    const int idx = it * 256 + tid;
    const int pos = idx >> 4, c4 = (idx & 15) * 4;
    ushort4 v = *(const ushort4*)&LT[pos][c4];
    *(ushort4*)&Yb[(size_t)pos * C8 + c4] = v;
  }
}

// ---------------------------------------------------------------------------
// phi + g projections v3 with FUSED 2x2 maxpool epilogue.
// Attn-fragment-blocked OUTPUT layouts (so attn_v8 loads are 1 KB coalesced):
//   gbf: [b][m/32][c2][32];  phT: [b][m/16][kc=2][16][32].
// R10 ERRATUM: the layout edit accidentally DROPPED the row-pair combine
// `v = fmaxf(v, Pbuf[...])` -> maxpool was horizontal-only -> absmax 2.92.
// Restored below (layout math itself re-verified element-wise, unchanged).
// grid (16, 5, 8).
// ---------------------------------------------------------------------------
__global__ __launch_bounds__(256)
void proj_pg3(const _Float16* __restrict__ Wph, const _Float16* __restrict__ Wpl,
              const _Float16* __restrict__ Wg, const _Float16* __restrict__ xT,
              _Float16* __restrict__ phT, unsigned short* __restrict__ gbf) {
  __shared__ float Pbuf[2][64][33];
  const int b = blockIdx.z, mt = blockIdx.y, tile = blockIdx.x;
  const int n0 = tile * 256;
  const int tid = threadIdx.x;
  const int w = tid >> 6, l = tid & 63;
  const int l15 = l & 15, quad = l >> 4;
  const bool isphi = (mt == 0);
  const _Float16* Ah = isphi ? Wph : (Wg + (size_t)(mt - 1) * 64 * CC);
  f32x4 acc[4][4] = {};
  const _Float16* Bbase = xT + (size_t)(b * CN + n0 + w * 64) * CC;

  auto loadB = [&](half8 (&bf)[4], int k0) {
#pragma unroll
    for (int j = 0; j < 4; ++j)
      bf[j] = *(const half8*)&Bbase[(size_t)(j * 16 + l15) * CC + k0 + quad * 8];
  };
  auto doK = [&](half8 (&bf)[4], int k0) {
    half8 ah[4];
#pragma unroll
    for (int i = 0; i < 4; ++i)
      ah[i] = *(const half8*)&Ah[(size_t)(i * 16 + l15) * CC + k0 + quad * 8];
#pragma unroll
    for (int i = 0; i < 4; ++i)
#pragma unroll
      for (int j = 0; j < 4; ++j)
        acc[i][j] = __builtin_amdgcn_mfma_f32_16x16x32_f16(ah[i], bf[j], acc[i][j], 0, 0, 0);
    if (isphi) {
      half8 al[4];
#pragma unroll
      for (int i = 0; i < 4; ++i)
        al[i] = *(const half8*)&Wpl[(size_t)(i * 16 + l15) * CC + k0 + quad * 8];
#pragma unroll
      for (int i = 0; i < 4; ++i)
#pragma unroll
        for (int j = 0; j < 4; ++j)
          acc[i][j] = __builtin_amdgcn_mfma_f32_16x16x32_f16(al[i], bf[j], acc[i][j], 0, 0, 0);
    }
  };

  half8 bfA[4], bfB[4];
  loadB(bfA, 0);
  for (int k0 = 0; k0 < CC; k0 += 64) {
    loadB(bfB, k0 + 32);          // prefetch chunk B
    doK(bfA, k0);                 // compute chunk A (B-load latency hides here)
    if (k0 + 64 < CC) loadB(bfA, k0 + 64);
    doK(bfB, k0 + 32);
  }
  // ---- pooled epilogue ----
  const bool owner = ((l15 & 1) == 0);
  const int colh = l15 >> 1;
  if (w & 1) {
#pragma unroll
    for (int i = 0; i < 4; ++i)
#pragma unroll
      for (int j = 0; j < 4; ++j)
#pragma unroll
        for (int r = 0; r < 4; ++r) {
          float v = acc[i][j][r];
          float o = __shfl_xor(v, 1);
          v = fmaxf(v, o);
          if (owner) Pbuf[w >> 1][i * 16 + quad * 4 + r][j * 8 + colh] = v;
        }
  }
  __syncthreads();
  if (!(w & 1)) {
    const int pr = tile * 2 + (w >> 1);
    unsigned short* phB = (unsigned short*)phT + (size_t)b * CM * C8;
    unsigned short* gBb = gbf + (size_t)b * C2 * CM;
#pragma unroll
    for (int i = 0; i < 4; ++i)
#pragma unroll
      for (int j = 0; j < 4; ++j)
#pragma unroll
        for (int r = 0; r < 4; ++r) {
          float v = acc[i][j][r];
          float o = __shfl_xor(v, 1);
          v = fmaxf(v, o);
          if (owner) {
            const int oc = i * 16 + quad * 4 + r;
            const int col = j * 8 + colh;       // m = pr*32 + col
            v = fmaxf(v, Pbuf[w >> 1][oc][col]);  // row-pair combine (RESTORED)
            if (isphi) {
              // phi[m][oc] -> [m/16][oc/32][m&15][oc&31]
              const int m = pr * 32 + col;
              phB[(((size_t)(m >> 4) * 2 + (oc >> 5)) << 9) +
                  ((m & 15) << 5) + (oc & 31)] = f16bits(v);
            } else {
              // g[c2][m] -> [m/32][c2][m&31]; jc = pr (col < 32)
              gBb[((size_t)pr * C2 + (mt - 1) * 64 + oc) * 32 + col] = f2bf(v);
            }
          }
        }
  }
}

// ---------------------------------------------------------------------------
// Fused attention v8 — v7 structure + FRAGMENT-BLOCKED global layouts.
// oproj_v5's staged-contiguous loads fixed its 69->~35 us pin (R9 validated);
// attn_v7 shares the same scattered-fragment-load pattern (gf: 16 rows x
// 64 B at 2048-B stride -> 2x line overfetch; pa: 16 rows at 128-B stride).
// v8 keeps the compute/exchange structure IDENTICAL but reads gbf/phT in
// fragment-blocked layouts: every gf/pa fragment load is one fully-coalesced
// 1-KB wave instruction. grid (64, 8).
// ---------------------------------------------------------------------------
__global__ __launch_bounds__(256, 2)
void attn_v8(const _Float16* __restrict__ thT, const _Float16* __restrict__ phT,
             const unsigned short* __restrict__ gbf,
             unsigned short* __restrict__ attbf) {
  __shared__ __align__(16) unsigned short Pl[2][4][16][40]; // [buf][qs][q][j+pad]
  __shared__ float Dinv[64];
  const int b = blockIdx.y;
  const int q0 = blockIdx.x * 64;
  const int tid = threadIdx.x;
  const int w = tid >> 6, l = tid & 63;
  const int l15 = l & 15, quad = l >> 4;
  half8 tb[2];
#pragma unroll
  for (int kc = 0; kc < 2; ++kc)
    tb[kc] = *(const half8*)&thT[(size_t)(b * CN + q0 + w * 16 + l15) * C8 +
                                 kc * 32 + quad * 8];
  f32x4 acc[4][4] = {};   // [qs][ct], wave's c2 = w*64 + ct*16 + l15
  float dnp = 0.f;        // numerator partials for qs == w only
  const unsigned short* phB = (const unsigned short*)phT + (size_t)b * CM * C8;
  const unsigned short* gB = gbf + (size_t)b * C2 * CM;

  auto loadc = [&](half8 (&pa)[2][2], short8 (&gf)[4], int j0) {
    // g frag: [jc][c2][32] — 1 KB contiguous per wave instruction
#pragma unroll
    for (int ct = 0; ct < 4; ++ct)
      gf[ct] = *(const short8*)&gB[((size_t)(j0 >> 5) * C2 +
                                    w * 64 + ct * 16 + l15) * 32 + quad * 8];
    // phi frag: [m/16][kc][16][32] — 1 KB contiguous per wave instruction
#pragma unroll
    for (int jt = 0; jt < 2; ++jt)
#pragma unroll
      for (int kc = 0; kc < 2; ++kc)
        pa[jt][kc] = *(const half8*)((const _Float16*)phB +
                       (((size_t)((j0 >> 4) + jt) * 2 + kc) << 9) +
                       (l15 << 5) + quad * 8);
  };
  auto step = [&](half8 (&pa)[2][2], short8 (&gf)[4], int buf) {
    f32x4 S0 = {0.f, 0.f, 0.f, 0.f}, S1 = {0.f, 0.f, 0.f, 0.f};
    S0 = __builtin_amdgcn_mfma_f32_16x16x32_f16(pa[0][0], tb[0], S0, 0, 0, 0);
    S0 = __builtin_amdgcn_mfma_f32_16x16x32_f16(pa[0][1], tb[1], S0, 0, 0, 0);
    S1 = __builtin_amdgcn_mfma_f32_16x16x32_f16(pa[1][0], tb[0], S1, 0, 0, 0);
    S1 = __builtin_amdgcn_mfma_f32_16x16x32_f16(pa[1][1], tb[1], S1, 0, 0, 0);
    float e0[4], e1[4];
#pragma unroll
    for (int r = 0; r < 4; ++r) { e0[r] = __expf(S0[r]); e1[r] = __expf(S1[r]); }
    dnp += (e0[0] + e0[1]) + (e0[2] + e0[3]) +
           (e1[0] + e1[1]) + (e1[2] + e1[3]);
    ushort4 w0, w1;
    w0.x = f2bf(e0[0]); w0.y = f2bf(e0[1]); w0.z = f2bf(e0[2]); w0.w = f2bf(e0[3]);
    w1.x = f2bf(e1[0]); w1.y = f2bf(e1[1]); w1.z = f2bf(e1[2]); w1.w = f2bf(e1[3]);
    *(ushort4*)&Pl[buf][w][l15][quad * 4] = w0;
    *(ushort4*)&Pl[buf][w][l15][16 + quad * 4] = w1;
    barrier_lds_only();
    short8 pfrag[4];
#pragma unroll
    for (int qs = 0; qs < 4; ++qs)
      pfrag[qs] = *(const short8*)&Pl[buf][qs][l15][quad * 8];
#pragma unroll
    for (int ct = 0; ct < 4; ++ct)
#pragma unroll
      for (int qs = 0; qs < 4; ++qs)
        acc[qs][ct] = __builtin_amdgcn_mfma_f32_16x16x32_bf16(pfrag[qs], gf[ct],
                                                              acc[qs][ct], 0, 0, 0);
  };

  half8 paA[2][2], paB[2][2];
  short8 gfA[4], gfB[4];
  loadc(paA, gfA, 0);
  for (int j0 = 0; j0 < CM; j0 += 64) {
    loadc(paB, gfB, j0 + 32);
    step(paA, gfA, 0);
    if (j0 + 64 < CM) loadc(paA, gfA, j0 + 64);
    step(paB, gfB, 1);
  }
  float d = dnp;
  d += __shfl_xor(d, 16);
  d += __shfl_xor(d, 32);
  if (quad == 0) Dinv[w * 16 + l15] = 1.0f / d;   // valid for q = l15
  __syncthreads();
  unsigned short* attB = attbf + (size_t)(b * CN + q0) * C2;
#pragma unroll
  for (int qs = 0; qs < 4; ++qs) {
#pragma unroll
    for (int r = 0; r < 4; ++r) {
      const int row = qs * 16 + quad * 4 + r;
      const float iv = Dinv[row];
#pragma unroll
      for (int ct = 0; ct < 4; ++ct)
        attB[(size_t)row * C2 + w * 64 + ct * 16 + l15] =
            f2bf(acc[qs][ct][r] * iv);
    }
  }
}

// ---------------------------------------------------------------------------
// Output projection v5 — LDS-STAGED GEMM. Validated R9: dropped out of the
// top-5 (was pinned 69-73 us across v2/v3/v4; total fell 34 us). Staged
// contiguous 512-B-row global reads + XOR-swizzled LDS fragments.
// LDS = 64 KiB -> 2 blocks/CU. Grid (64, 8, 8).
// ---------------------------------------------------------------------------
__global__ __launch_bounds__(256, 2)
void oproj_v5(const unsigned short* __restrict__ woh,
              const unsigned short* __restrict__ attbf,
              const float* __restrict__ X, const float* __restrict__ gamma,
              float* __restrict__ out) {
  __shared__ __align__(16) unsigned short smem[2 * 64 * 256];  // 64 KiB
  unsigned short* As = smem;             // [64][256] shorts, XOR-swizzled rows
  unsigned short* Bs = smem + 64 * 256;  // [64][256]
  float* Twf = (float*)smem;             // epilogue overlay [2][4][16][36]
  const int b = blockIdx.z, mt = blockIdx.y, n0 = blockIdx.x * 64;
  const int tid = threadIdx.x;
  const int w = tid >> 6, l = tid & 63;
  const int l15 = l & 15, quad = l >> 4;
  const int wc = w >> 1, wn = w & 1;     // wave -> (c-half, n-half)

  // ---- stage A (Wo rows mt*64..+63) and B (attbf rows n0..+63), K=256 ----
  const unsigned short* Asrc = woh + (size_t)(mt * 64) * C2;
  const unsigned short* Bsrc = attbf + ((size_t)b * CN + n0) * C2;
  uint4 ra[8], rb[8];
#pragma unroll
  for (int s = 0; s < 8; ++s) {
    const int idx = s * 256 + tid;       // 0..2047 over 64 rows x 32 slots
    const int row = idx >> 5, sl = idx & 31;
    ra[s] = *(const uint4*)&Asrc[(size_t)row * C2 + sl * 8];
    rb[s] = *(const uint4*)&Bsrc[(size_t)row * C2 + sl * 8];
  }
  __builtin_amdgcn_sched_barrier(0);     // keep all 16 loads issued up-front
#pragma unroll
  for (int s = 0; s < 8; ++s) {
    const int idx = s * 256 + tid;
    const int row = idx >> 5, sl = idx & 31;
    const int sw = sl ^ (row & 7);       // XOR-swizzle (write side)
    *(uint4*)&As[row * 256 + sw * 8] = ra[s];
    *(uint4*)&Bs[row * 256 + sw * 8] = rb[s];
  }
  __syncthreads();

  // ---- MFMA phase: acc[2][2] per wave over its 32x32 quadrant ----
  f32x4 acc[2][2] = {};
#pragma unroll
  for (int kk = 0; kk < 8; ++kk) {
    const int sbase = kk * 4 + quad;     // slot = k0/8 + quad (pre-swizzle)
    short8 af[2], bf[2];
#pragma unroll
    for (int i = 0; i < 2; ++i) {
      const int row = wc * 32 + i * 16 + l15;
      af[i] = *(const short8*)&As[row * 256 + ((sbase ^ (row & 7)) * 8)];
    }
#pragma unroll
    for (int j = 0; j < 2; ++j) {
      const int row = wn * 32 + j * 16 + l15;
      bf[j] = *(const short8*)&Bs[row * 256 + ((sbase ^ (row & 7)) * 8)];
    }
#pragma unroll
    for (int i = 0; i < 2; ++i)
#pragma unroll
      for (int j = 0; j < 2; ++j)
        acc[i][j] = __builtin_amdgcn_mfma_f32_16x16x32_bf16(af[i], bf[j],
                                                            acc[i][j], 0, 0, 0);
  }
  __syncthreads();   // all waves' LDS reads done before Tw overlay writes

  // ---- epilogue: wave-local Tw transpose, float4 X+out streaming ----
  const float gm = gamma[0];
  const int cp = l >> 2, nq = (l & 3) * 8;
  // Tw layout: ((i*4 + w)*16 + r)*36 + col  (pad 36 -> 16B-aligned rows)
#pragma unroll
  for (int i = 0; i < 2; ++i)
#pragma unroll
    for (int j = 0; j < 2; ++j)
#pragma unroll
      for (int r = 0; r < 4; ++r)
        Twf[((i * 4 + w) * 16 + quad * 4 + r) * 36 + j * 16 + l15] = acc[i][j][r];
#pragma unroll
  for (int i = 0; i < 2; ++i) {
    const float4 v0 = *(const float4*)&Twf[((i * 4 + w) * 16 + cp) * 36 + nq];
    const float4 v1 = *(const float4*)&Twf[((i * 4 + w) * 16 + cp) * 36 + nq + 4];
    const int c = mt * 64 + wc * 32 + i * 16 + cp;
    const size_t idx = ((size_t)b * CC + c) * CN + n0 + wn * 32 + nq;
    const float4 x0 = *(const float4*)&X[idx];
    const float4 x1 = *(const float4*)&X[idx + 4];
    float4 o0, o1;
    o0.x = x0.x + gm * v0.x; o0.y = x0.y + gm * v0.y;
    o0.z = x0.z + gm * v0.z; o0.w = x0.w + gm * v0.w;
    o1.x = x1.x + gm * v1.x; o1.y = x1.y + gm * v1.y;
    o1.z = x1.z + gm * v1.z; o1.w = x1.w + gm * v1.w;
    *(float4*)&out[idx] = o0;
    *(float4*)&out[idx + 4] = o1;
  }
}

// ---------------------------------------------------------------------------
extern "C" void kernel_launch(void* const* d_in, const int* in_sizes, int n_in,
                              void* d_out, int out_size, void* d_ws, size_t ws_size,
                              hipStream_t stream) {
  const float* x       = (const float*)d_in[0];
  const float* w_theta = (const float*)d_in[1];
  const float* w_phi   = (const float*)d_in[2];
  const float* w_g     = (const float*)d_in[3];
  const float* w_o     = (const float*)d_in[4];
  const float* gamma   = (const float*)d_in[5];
  float* out = (float*)d_out;
  char* wsb = (char*)d_ws;

  // Workspace layout (bytes), total 43,778,048:
  _Float16*       xT    = (_Float16*)(wsb + 0);          // 32 MiB [B,4096,512]
  _Float16*       thT   = (_Float16*)(wsb + 33554432);   //  4 MiB [B,4096,64]
  _Float16*       phT   = (_Float16*)(wsb + 37748736);   //  1 MiB fragment-blocked
  unsigned short* gbf   = (unsigned short*)(wsb + 38797312); // 4 MiB j-chunk-blocked
  _Float16*       wth   = (_Float16*)(wsb + 42991616);
  _Float16*       wtl   = (_Float16*)(wsb + 43057152);
  _Float16*       wph   = (_Float16*)(wsb + 43122688);
  _Float16*       wpl   = (_Float16*)(wsb + 43188224);
  _Float16*       wgf   = (_Float16*)(wsb + 43253760);
  unsigned short* woh   = (unsigned short*)(wsb + 43515904);
  unsigned short* attbf = (unsigned short*)(wsb + 0);    // 16 MiB, aliases xT (dead)

  dim3 blk(256);
  conv_w<<<512, blk, 0, stream>>>(w_theta, w_phi, w_g, w_o,
                                  wth, wtl, wph, wpl, wgf, woh);
  xpose<<<dim3(64, 8, CB), blk, 0, stream>>>(x, xT);
  proj_th2<<<dim3(128, CB), blk, 0, stream>>>(wth, wtl, xT, thT);
  proj_pg3<<<dim3(16, 5, CB), blk, 0, stream>>>(wph, wpl, wgf, xT, phT, gbf);
  attn_v8<<<dim3(64, CB), blk, 0, stream>>>(thT, phT, gbf, attbf);
  oproj_v5<<<dim3(64, 8, CB), blk, 0, stream>>>(woh, attbf, x, gamma, out);
}